// Round 9
// baseline (310.749 us; speedup 1.0000x reference)
//
#include <hip/hip_runtime.h>
#include <stdint.h>

#define IN_DIM 512
#define NT 64
#define AH 128
#define NCLS 10
#define BN_EPS_C 1e-5f
#define SHRINK 0.3f
#define DSTRIDE 67  // decw leading dim (67%32=3 coprime -> 2-way-free banking)

typedef __bf16 bf16x8 __attribute__((ext_vector_type(8)));
typedef float f32x4 __attribute__((ext_vector_type(4)));
typedef unsigned int u32x4 __attribute__((ext_vector_type(4)));

__device__ __forceinline__ unsigned short f2bf(float f) {
  unsigned u = __builtin_bit_cast(unsigned, f);
  u += 0x7fffu + ((u >> 16) & 1u);   // RNE; inputs are NaN-free after NaN-zeroing
  return (unsigned short)(u >> 16);
}

__device__ __forceinline__ float bflo(unsigned w) {
  return __builtin_bit_cast(float, w << 16);
}
__device__ __forceinline__ float bfhi(unsigned w) {
  return __builtin_bit_cast(float, w & 0xffff0000u);
}

__device__ __forceinline__ void gload_lds16(const void* g, void* l) {
  __builtin_amdgcn_global_load_lds(
      (const __attribute__((address_space(1))) void*)g,
      (__attribute__((address_space(3))) void*)l, 16, 0, 0);
}

// read one 16B MFMA fragment from a swizzled [rows][64] bf16 LDS tile
__device__ __forceinline__ bf16x8 frag_ld(const char* lds, int r, int q) {
  return *reinterpret_cast<const bf16x8*>(lds + r * 128 + ((q ^ (r & 7)) * 16));
}

// ---------------- fused prep: x->bf16+flags, tree_w->bf16(pad), w1->w1t ----
__global__ void __launch_bounds__(256) k_prep(
    const float* __restrict__ x, unsigned short* __restrict__ xc, float* __restrict__ flags,
    const float* __restrict__ tw, unsigned short* __restrict__ twb,
    const float* __restrict__ w1, unsigned short* __restrict__ w1t) {
  int b = blockIdx.x;
  if (b < 4096) {
    int wid = threadIdx.x >> 6, lane = threadIdx.x & 63;
    int row = b * 4 + wid;
    const float* px = x + row * IN_DIM + lane * 8;
    float4 a = *(const float4*)px;
    float4 bb = *(const float4*)(px + 4);
    float v[8] = {a.x, a.y, a.z, a.w, bb.x, bb.y, bb.z, bb.w};
    bool nan_any = false;
    union { unsigned short s[8]; u32x4 u; } pk;
#pragma unroll
    for (int i = 0; i < 8; i++) {
      bool n = (v[i] != v[i]);
      nan_any |= n;
      pk.s[i] = f2bf(n ? 0.f : v[i]);
    }
    *reinterpret_cast<u32x4*>(xc + row * IN_DIM + lane * 8) = pk.u;
    unsigned long long bal = __ballot(nan_any);
    if (lane == 0) flags[row] = bal ? 1.f : 0.f;
  } else if (b < 5120) {
    int tid = (b - 4096) * 256 + threadIdx.x;  // 262144
    int o = tid * 8;
    int k = o & 511;
    int nt = o >> 9;
    int node = nt & 63, t = nt >> 6;
    union { unsigned short s[8]; u32x4 u; } pk;
    if (node < 63) {
      const float* p = tw + ((t * 63 + node) * 512 + k);
      float4 a = *(const float4*)p, bb = *(const float4*)(p + 4);
      float v[8] = {a.x, a.y, a.z, a.w, bb.x, bb.y, bb.z, bb.w};
#pragma unroll
      for (int i = 0; i < 8; i++) pk.s[i] = f2bf(v[i]);
    } else {
#pragma unroll
      for (int i = 0; i < 8; i++) pk.s[i] = 0;
    }
    *reinterpret_cast<u32x4*>(twb + o) = pk.u;
  } else {
    int tid = (b - 5120) * 256 + threadIdx.x;  // 65536
    int k = tid & 511, n = tid >> 9;
    w1t[n * 512 + k] = f2bf(w1[k * 128 + n]);
  }
}

// ---------------- fused attention (unchanged from round 8) ----------------
__global__ void __launch_bounds__(256) k_attn(
    const unsigned short* __restrict__ xc, const unsigned short* __restrict__ w1t,
    const float* __restrict__ b1, const float* __restrict__ gam,
    const float* __restrict__ bet, const float* __restrict__ mu,
    const float* __restrict__ var, const float* __restrict__ w2,
    const float* __restrict__ b2, const float* __restrict__ rw,
    float* __restrict__ wbt) {
  __shared__ __align__(16) char smem[59392];
  char* As = smem;                                        // 64x64 bf16 = 8192
  char* Bs = smem + 8192;                                 // 128x64 bf16 = 16384
  unsigned short* hb  = (unsigned short*)(smem + 24576);  // [64][136] bf16 = 17408
  unsigned short* w2s = (unsigned short*)(smem + 41984);  // [64][136] bf16 = 17408
  int lane = threadIdx.x & 63, wid = threadIdx.x >> 6;
  int bm0 = blockIdx.x * 64;
  int m = lane & 15, q = lane >> 4;
  int sub = lane >> 3, cpos = lane & 7;

  for (int i = threadIdx.x; i < AH * NT; i += 256) {
    int k = i >> 6, n = i & 63;
    w2s[n * 136 + k] = f2bf(w2[i]);
  }

  f32x4 acc[8];
#pragma unroll
  for (int j = 0; j < 8; j++) acc[j] = f32x4{0.f, 0.f, 0.f, 0.f};
  const unsigned short* Ag = xc + (size_t)bm0 * 512;

  for (int ko = 0; ko < 8; ++ko) {
    const unsigned short* Ak = Ag + ko * 64;
    const unsigned short* Bk = w1t + ko * 64;
#pragma unroll
    for (int i = 0; i < 2; i++) {
      int seg = wid * 2 + i;
      int r = seg * 8 + sub;
      int cg = cpos ^ (r & 7);
      gload_lds16(Ak + r * 512 + cg * 8, As + seg * 1024);
    }
#pragma unroll
    for (int i = 0; i < 4; i++) {
      int seg = wid * 4 + i;
      int r = seg * 8 + sub;
      int cg = cpos ^ (r & 7);
      gload_lds16(Bk + r * 512 + cg * 8, Bs + seg * 1024);
    }
    __syncthreads();
#pragma unroll
    for (int ks = 0; ks < 2; ++ks) {
      bf16x8 af = frag_ld(As, wid * 16 + m, ks * 4 + q);
#pragma unroll
      for (int ni = 0; ni < 8; ni++) {
        bf16x8 bfr = frag_ld(Bs, ni * 16 + m, ks * 4 + q);
        acc[ni] = __builtin_amdgcn_mfma_f32_16x16x32_bf16(af, bfr, acc[ni], 0, 0, 0);
      }
    }
    __syncthreads();
  }

#pragma unroll
  for (int ni = 0; ni < 8; ni++) {
    int col = ni * 16 + m;
    float bb = b1[col], ga = gam[col], be = bet[col], mm = mu[col];
    float iv = rsqrtf(var[col] + BN_EPS_C);
#pragma unroll
    for (int r4 = 0; r4 < 4; r4++) {
      int rl = wid * 16 + q * 4 + r4;
      float v = acc[ni][r4] + bb;
      v = fmaxf(v, 0.f);
      v = (v - mm) * iv * ga + be;
      hb[rl * 136 + col] = f2bf(v);
    }
  }

  f32x4 acc2[4];
#pragma unroll
  for (int nt = 0; nt < 4; nt++) acc2[nt] = f32x4{0.f, 0.f, 0.f, 0.f};
#pragma unroll
  for (int ks = 0; ks < 4; ++ks) {
    bf16x8 af = *reinterpret_cast<const bf16x8*>(hb + (wid * 16 + m) * 136 + ks * 32 + q * 8);
#pragma unroll
    for (int nt = 0; nt < 4; nt++) {
      bf16x8 bfr = *reinterpret_cast<const bf16x8*>(w2s + (nt * 16 + m) * 136 + ks * 32 + q * 8);
      acc2[nt] = __builtin_amdgcn_mfma_f32_16x16x32_bf16(af, bfr, acc2[nt], 0, 0, 0);
    }
  }

  float b2v[4], cfv[4];
#pragma unroll
  for (int nt = 0; nt < 4; nt++) {
    int col = nt * 16 + m;
    b2v[nt] = b2[col];
    cfv[nt] = SHRINK * rw[col];
  }
#pragma unroll
  for (int reg = 0; reg < 4; ++reg) {
    float s0 = acc2[0][reg] + b2v[0];
    float s1 = acc2[1][reg] + b2v[1];
    float s2 = acc2[2][reg] + b2v[2];
    float s3 = acc2[3][reg] + b2v[3];
    float mx = fmaxf(fmaxf(s0, s1), fmaxf(s2, s3));
#pragma unroll
    for (int o = 1; o < 16; o <<= 1) mx = fmaxf(mx, __shfl_xor(mx, o));
    float e0 = __expf(s0 - mx), e1 = __expf(s1 - mx);
    float e2 = __expf(s2 - mx), e3 = __expf(s3 - mx);
    float sm = e0 + e1 + e2 + e3;
#pragma unroll
    for (int o = 1; o < 16; o <<= 1) sm += __shfl_xor(sm, o);
    float inv = 1.f / sm;
    int row = bm0 + wid * 16 + q * 4 + reg;
    wbt[row * NT + m]      = e0 * inv * cfv[0];
    wbt[row * NT + 16 + m] = e1 * inv * cfv[1];
    wbt[row * NT + 32 + m] = e2 * inv * cfv[2];
    wbt[row * NT + 48 + m] = e3 * inv * cfv[3];
  }
}

// ---------------- main: tree logits + routing + MFMA leaf reduce ----------
// GEMM part unchanged (R7-verified). Epilogue v2: routing probs scaled by w,
// packed bf16 into MFMA-A layout in the retired decw region (same XOR-16B
// swizzle as GEMM tiles -> frag_ld reused), leaf staged once as B-operand
// [class][leaf] bf16 (stride 72, disjoint 4.6 KB); 4 MFMA/wave/tree accumulate
// C[row][class] across both trees; C-layout lanes m<10 store part directly.
// Replaces the 350-fma/thread/tree leaf dot + redbuf combine.
// Constraints kept: no atomics (R3), no VGPR cap (R2), no LDS leaf VGPR blowup
// (R5: keep leaf/routing operands out of long-lived VGPRs).
__global__ void __launch_bounds__(256) k_trees(
    const unsigned short* __restrict__ xc,   // [16384][512]
    const unsigned short* __restrict__ twb,  // [64*64][512]
    const float* __restrict__ tree_b,        // [64][63]
    const float* __restrict__ tree_temp,     // [64]
    const float* __restrict__ leaf,          // [64][64][10]
    const float* __restrict__ wbt,           // [16384][64]
    const float* __restrict__ flags,         // [16384]
    unsigned short* __restrict__ part) {     // [16384][32][10] bf16
  __shared__ __align__(16) char smem[39424];
  char* As = smem;                                  // 128x64 bf16 = 16384 (GEMM)
  char* Bs = smem + 16384;                          // 128x64 bf16 = 16384 (GEMM)
  float* decw = reinterpret_cast<float*>(smem);     // 128 x 67 f32 = 34304 (epi)
  unsigned short* leafb = (unsigned short*)(smem + 34816);  // [2][16][72] bf16 = 4608
  int lane = threadIdx.x & 63, wid = threadIdx.x >> 6;
  int bm0 = blockIdx.y * 128;   // row tile
  int t0 = blockIdx.x * 2;      // tree pair (fast grid dim for L2 sharing)
  int m = lane & 15, q = lane >> 4;
  int sub = lane >> 3, cpos = lane & 7;
  int rA0 = wid * 32 + m;
  int row_l = threadIdx.x & 127;
  int h = __builtin_amdgcn_readfirstlane((int)(threadIdx.x >> 7));  // wave-uniform half
  int grow = bm0 + row_l;

  // stage leaf as B-operand: leafb[tt][n=class(16, pad0)][k=leaf(64)]
  for (int i = threadIdx.x; i < 2048; i += 256) {
    int tt = i >> 10, n = (i >> 6) & 15, k = i & 63;
    float v = (n < 10) ? leaf[(t0 + tt) * 640 + k * 10 + n] : 0.f;
    leafb[(tt * 16 + n) * 72 + k] = f2bf(v);
  }

  f32x4 acc[2][8];
#pragma unroll
  for (int i = 0; i < 2; i++)
#pragma unroll
    for (int j = 0; j < 8; j++) acc[i][j] = f32x4{0.f, 0.f, 0.f, 0.f};

  const unsigned short* Ag = xc + (size_t)bm0 * 512;
  const unsigned short* Bg = twb + (size_t)t0 * 64 * 512;

  for (int ko = 0; ko < 8; ++ko) {
    const unsigned short* Ak = Ag + ko * 64;
    const unsigned short* Bk = Bg + ko * 64;
#pragma unroll
    for (int i = 0; i < 4; i++) {
      int seg = wid * 4 + i;
      int r = seg * 8 + sub;
      int cg = cpos ^ (r & 7);
      gload_lds16(Ak + r * 512 + cg * 8, As + seg * 1024);
      gload_lds16(Bk + r * 512 + cg * 8, Bs + seg * 1024);
    }
    __syncthreads();
#pragma unroll
    for (int ks = 0; ks < 2; ++ks) {
      bf16x8 af[2];
#pragma unroll
      for (int mi = 0; mi < 2; mi++) af[mi] = frag_ld(As, rA0 + mi * 16, ks * 4 + q);
#pragma unroll
      for (int ni = 0; ni < 8; ni++) {
        bf16x8 bfr = frag_ld(Bs, ni * 16 + m, ks * 4 + q);
#pragma unroll
        for (int mi = 0; mi < 2; mi++)
          acc[mi][ni] = __builtin_amdgcn_mfma_f32_16x16x32_bf16(af[mi], bfr, acc[mi][ni], 0, 0, 0);
      }
    }
    __syncthreads();
  }

  // ---- epilogue ----
  float flv[2][4];
  {
    float4 f0 = *(const float4*)(flags + bm0 + wid * 32 + q * 4);
    float4 f1 = *(const float4*)(flags + bm0 + wid * 32 + 16 + q * 4);
    flv[0][0] = f0.x; flv[0][1] = f0.y; flv[0][2] = f0.z; flv[0][3] = f0.w;
    flv[1][0] = f1.x; flv[1][1] = f1.y; flv[1][2] = f1.z; flv[1][3] = f1.w;
  }
  float2 wpair = *(const float2*)(wbt + grow * 64 + t0);  // per-row tree weights

  f32x4 acc3[2];  // C[row][class], accumulated across BOTH trees (w in A)
  acc3[0] = f32x4{0.f, 0.f, 0.f, 0.f};
  acc3[1] = f32x4{0.f, 0.f, 0.f, 0.f};

  for (int tt = 0; tt < 2; ++tt) {
    int t = t0 + tt;
    float itemp = 1.f / tree_temp[t];
    float tbv[4];
#pragma unroll
    for (int nl = 0; nl < 4; nl++) {
      int node = nl * 16 + m;
      tbv[nl] = (node < 63) ? tree_b[t * 63 + node] : 0.f;
    }
    __syncthreads();  // previous MFMA/GEMM readers of decw region done
    // sigmoid decisions -> LDS, level-grouped offset node+1, miss applied here
#pragma unroll
    for (int mi = 0; mi < 2; mi++) {
#pragma unroll
      for (int nl = 0; nl < 4; nl++) {
        int node = nl * 16 + m;
        f32x4 a = acc[mi][tt * 4 + nl];
#pragma unroll
        for (int r4 = 0; r4 < 4; r4++) {
          int row = wid * 32 + mi * 16 + q * 4 + r4;
          float z = (a[r4] + tbv[nl]) * itemp;
          float sig = __builtin_amdgcn_rcpf(1.f + __expf(-z));
          decw[row * DSTRIDE + node + 1] = (flv[mi][r4] != 0.f) ? 0.5f : sig;
        }
      }
    }
    __syncthreads();

    const float* dr = decw + row_l * DSTRIDE;
    float R[16];
    {
      float d0 = dr[1];
      R[0] = d0;
      R[1] = 1.f - d0;
    }
#pragma unroll
    for (int L = 1; L <= 3; ++L) {
      int half = 1 << L;
#pragma unroll
      for (int g = 0; g < half; g += 2) {
        float2 dd = *reinterpret_cast<const float2*>(dr + half + g);
        float ra = R[g] * dd.x;
        R[g + half] = R[g] - ra;
        R[g] = ra;
        float rb = R[g + 1] * dd.y;
        R[g + 1 + half] = R[g + 1] - rb;
        R[g + 1] = rb;
      }
    }
    // level 4: keep only children with bit4 == h
#pragma unroll
    for (int p = 0; p < 16; p += 2) {
      float2 dd = *reinterpret_cast<const float2*>(dr + 16 + p);
      float da = h ? (1.f - dd.x) : dd.x;
      float db = h ? (1.f - dd.y) : dd.y;
      R[p] *= da;
      R[p + 1] *= db;
    }
    // read level-5 decisions BEFORE retiring decw
    float2 d5[8];
#pragma unroll
    for (int pp = 0; pp < 8; pp++)
      d5[pp] = *reinterpret_cast<const float2*>(dr + 32 + 16 * h + pp * 2);
    __syncthreads();  // all decw reads done; region becomes A_s

    // scaled leaf-probs (w folded in), bf16-packed; leaf l = 16h+p (L) / +32 (R)
    float w = tt ? wpair.y : wpair.x;
    unsigned pkL[8], pkR[8];
#pragma unroll
    for (int pp = 0; pp < 8; pp++) {
      float rla = R[2 * pp] * d5[pp].x;
      float rlb = R[2 * pp + 1] * d5[pp].y;
      float rra = R[2 * pp] - rla;
      float rrb = R[2 * pp + 1] - rlb;
      pkL[pp] = (unsigned)f2bf(w * rla) | ((unsigned)f2bf(w * rlb) << 16);
      pkR[pp] = (unsigned)f2bf(w * rra) | ((unsigned)f2bf(w * rrb) << 16);
    }
    // write A_s[row][64 leaves] bf16 in 16B chunks, GEMM-style XOR swizzle
    {
      char* As_ = smem;
      int sw = row_l & 7;
      u32x4 v0{pkL[0], pkL[1], pkL[2], pkL[3]};
      u32x4 v1{pkL[4], pkL[5], pkL[6], pkL[7]};
      u32x4 v2{pkR[0], pkR[1], pkR[2], pkR[3]};
      u32x4 v3{pkR[4], pkR[5], pkR[6], pkR[7]};
      *(u32x4*)(As_ + row_l * 128 + (((2 * h) ^ sw) * 16)) = v0;
      *(u32x4*)(As_ + row_l * 128 + (((2 * h + 1) ^ sw) * 16)) = v1;
      *(u32x4*)(As_ + row_l * 128 + (((4 + 2 * h) ^ sw) * 16)) = v2;
      *(u32x4*)(As_ + row_l * 128 + (((5 + 2 * h) ^ sw) * 16)) = v3;
    }
    __syncthreads();
    // MFMA leaf reduce: C[row][class] += A_s . leafb^T  (4 per wave)
#pragma unroll
    for (int mt = 0; mt < 2; mt++) {
#pragma unroll
      for (int ks = 0; ks < 2; ks++) {
        bf16x8 af = frag_ld(smem, wid * 32 + mt * 16 + m, ks * 4 + q);
        bf16x8 bfr = *reinterpret_cast<const bf16x8*>(
            leafb + (tt * 16 + m) * 72 + ks * 32 + q * 8);
        acc3[mt] = __builtin_amdgcn_mfma_f32_16x16x32_bf16(af, bfr, acc3[mt], 0, 0, 0);
      }
    }
  }

  // direct C-layout store: lane m<10 owns class m for its 8 rows
  if (m < 10) {
#pragma unroll
    for (int mt = 0; mt < 2; mt++) {
#pragma unroll
      for (int reg = 0; reg < 4; reg++) {
        int row = bm0 + wid * 32 + mt * 16 + q * 4 + reg;
        part[((size_t)row * 32 + blockIdx.x) * 10 + m] = f2bf(acc3[mt][reg]);
      }
    }
  }
}

// ---------------- final: reduce 32 bf16 slices + softmax ----------------
// 128 blocks x 128 threads (R8's 64 blocks used only 64 CUs).
__global__ void __launch_bounds__(128) k_finish(const unsigned short* __restrict__ part,
                                               float* __restrict__ out) {
  int row = blockIdx.x * 128 + threadIdx.x;
  const uint4* pu = reinterpret_cast<const uint4*>(part + (size_t)row * 320);
  float v[10];
#pragma unroll
  for (int c = 0; c < 10; c++) v[c] = 0.f;
#pragma unroll
  for (int ch = 0; ch < 8; ++ch) {
    uint4 w0 = pu[ch * 5 + 0];
    uint4 w1 = pu[ch * 5 + 1];
    uint4 w2 = pu[ch * 5 + 2];
    uint4 w3 = pu[ch * 5 + 3];
    uint4 w4 = pu[ch * 5 + 4];
    unsigned dw[20] = {w0.x, w0.y, w0.z, w0.w, w1.x, w1.y, w1.z, w1.w,
                       w2.x, w2.y, w2.z, w2.w, w3.x, w3.y, w3.z, w3.w,
                       w4.x, w4.y, w4.z, w4.w};
#pragma unroll
    for (int d = 0; d < 20; d++) {
      int k = d % 5;
      v[2 * k] += bflo(dw[d]);
      v[2 * k + 1] += bfhi(dw[d]);
    }
  }
  float mx = -1e30f;
#pragma unroll
  for (int c = 0; c < 10; c++) mx = fmaxf(mx, v[c]);
  float sm = 0.f;
#pragma unroll
  for (int c = 0; c < 10; c++) {
    v[c] = __expf(v[c] - mx);
    sm += v[c];
  }
  float inv = 1.f / sm;
#pragma unroll
  for (int c = 0; c < 10; c++) out[row * 10 + c] = v[c] * inv;
}

extern "C" void kernel_launch(void* const* d_in, const int* in_sizes, int n_in,
                              void* d_out, int out_size, void* d_ws, size_t ws_size,
                              hipStream_t stream) {
  const float* x    = (const float*)d_in[0];
  const float* w1   = (const float*)d_in[1];
  const float* b1   = (const float*)d_in[2];
  const float* gam  = (const float*)d_in[3];
  const float* bet  = (const float*)d_in[4];
  const float* mu   = (const float*)d_in[5];
  const float* var  = (const float*)d_in[6];
  const float* w2   = (const float*)d_in[7];
  const float* b2   = (const float*)d_in[8];
  const float* tw   = (const float*)d_in[9];
  const float* tb   = (const float*)d_in[10];
  const float* temp = (const float*)d_in[11];
  const float* leaf = (const float*)d_in[12];
  const float* rw   = (const float*)d_in[13];
  float* out = (float*)d_out;

  char* ws = (char*)d_ws;
  unsigned short* xc  = (unsigned short*)(ws);             // 16,777,216 B
  unsigned short* twb = (unsigned short*)(ws + 16777216);  //  4,194,304 B
  unsigned short* w1t = (unsigned short*)(ws + 20971520);  //    131,072 B
  float* wbt  = (float*)(ws + 21102592);                   //  4,194,304 B
  float* flg  = (float*)(ws + 25296896);                   //     65,536 B
  unsigned short* part = (unsigned short*)(ws + 25362432); // 10,485,760 B

  k_prep<<<5376, 256, 0, stream>>>(x, xc, flg, tw, twb, w1, w1t);
  k_attn<<<256, 256, 0, stream>>>(xc, w1t, b1, gam, bet, mu, var, w2, b2, rw, wbt);
  dim3 g2(32, 128);
  k_trees<<<g2, 256, 0, stream>>>(xc, twb, tb, temp, leaf, wbt, flg, part);
  k_finish<<<128, 128, 0, stream>>>(part, out);
}

// Round 10
// 287.825 us; speedup vs baseline: 1.0796x; 1.0796x over previous
//
#include <hip/hip_runtime.h>
#include <stdint.h>

#define IN_DIM 512
#define NT 64
#define AH 128
#define NCLS 10
#define BN_EPS_C 1e-5f
#define SHRINK 0.3f
#define DSTRIDE 67  // decw leading dim (67%32=3 coprime -> 2-way-free banking)

typedef __bf16 bf16x8 __attribute__((ext_vector_type(8)));
typedef float f32x4 __attribute__((ext_vector_type(4)));
typedef unsigned int u32x4 __attribute__((ext_vector_type(4)));

__device__ __forceinline__ unsigned short f2bf(float f) {
  unsigned u = __builtin_bit_cast(unsigned, f);
  u += 0x7fffu + ((u >> 16) & 1u);   // RNE; inputs are NaN-free after NaN-zeroing
  return (unsigned short)(u >> 16);
}

__device__ __forceinline__ float bflo(unsigned w) {
  return __builtin_bit_cast(float, w << 16);
}
__device__ __forceinline__ float bfhi(unsigned w) {
  return __builtin_bit_cast(float, w & 0xffff0000u);
}

__device__ __forceinline__ void gload_lds16(const void* g, void* l) {
  __builtin_amdgcn_global_load_lds(
      (const __attribute__((address_space(1))) void*)g,
      (__attribute__((address_space(3))) void*)l, 16, 0, 0);
}

// read one 16B MFMA fragment from a swizzled [rows][64] bf16 LDS tile
__device__ __forceinline__ bf16x8 frag_ld(const char* lds, int r, int q) {
  return *reinterpret_cast<const bf16x8*>(lds + r * 128 + ((q ^ (r & 7)) * 16));
}

// ---------------- prep: tree_w->bf16(pad), w1->w1t (x handled in k_attn) ----
__global__ void __launch_bounds__(256) k_prep(
    const float* __restrict__ tw, unsigned short* __restrict__ twb,
    const float* __restrict__ w1, unsigned short* __restrict__ w1t) {
  int b = blockIdx.x;
  if (b < 1024) {
    int tid = b * 256 + threadIdx.x;  // 262144
    int o = tid * 8;
    int k = o & 511;
    int nt = o >> 9;
    int node = nt & 63, t = nt >> 6;
    union { unsigned short s[8]; u32x4 u; } pk;
    if (node < 63) {
      const float* p = tw + ((t * 63 + node) * 512 + k);
      float4 a = *(const float4*)p, bb = *(const float4*)(p + 4);
      float v[8] = {a.x, a.y, a.z, a.w, bb.x, bb.y, bb.z, bb.w};
#pragma unroll
      for (int i = 0; i < 8; i++) pk.s[i] = f2bf(v[i]);
    } else {
#pragma unroll
      for (int i = 0; i < 8; i++) pk.s[i] = 0;
    }
    *reinterpret_cast<u32x4*>(twb + o) = pk.u;
  } else {
    int tid = (b - 1024) * 256 + threadIdx.x;  // 65536
    int k = tid & 511, n = tid >> 9;
    w1t[n * 512 + k] = f2bf(w1[k * 128 + n]);
  }
}

// ---------------- fused attention + x conversion ----------------
// Phase 0: convert this block's 64 rows of x -> xc bf16 (NaN->0) + flags,
// coalesced (wave = one row per iter). __syncthreads() drains vmcnt so the
// K-loop's global_load_lds sees the fresh xc through the same-XCD L2.
// Then: h = BN(relu(x@w1+b1)) via MFMA; attn=softmax(h@w2+b2) via MFMA;
// wbt = attn*SHRINK*rw. (R8-verified GEMM structure.)
__global__ void __launch_bounds__(256) k_attn(
    const float* __restrict__ x, unsigned short* __restrict__ xc,
    float* __restrict__ flags,
    const unsigned short* __restrict__ w1t,
    const float* __restrict__ b1, const float* __restrict__ gam,
    const float* __restrict__ bet, const float* __restrict__ mu,
    const float* __restrict__ var, const float* __restrict__ w2,
    const float* __restrict__ b2, const float* __restrict__ rw,
    float* __restrict__ wbt) {
  __shared__ __align__(16) char smem[59392];
  char* As = smem;                                        // 64x64 bf16 = 8192
  char* Bs = smem + 8192;                                 // 128x64 bf16 = 16384
  unsigned short* hb  = (unsigned short*)(smem + 24576);  // [64][136] bf16 = 17408
  unsigned short* w2s = (unsigned short*)(smem + 41984);  // [64][136] bf16 = 17408
  int lane = threadIdx.x & 63, wid = threadIdx.x >> 6;
  int bm0 = blockIdx.x * 64;
  int m = lane & 15, q = lane >> 4;
  int sub = lane >> 3, cpos = lane & 7;

  // phase 0: x -> xc + flags for this block's 64 rows
  for (int i = 0; i < 16; ++i) {
    int r = bm0 + wid * 16 + i;
    const float* px = x + (size_t)r * 512 + lane * 8;
    float4 a = *(const float4*)px;
    float4 bb = *(const float4*)(px + 4);
    float v[8] = {a.x, a.y, a.z, a.w, bb.x, bb.y, bb.z, bb.w};
    bool nan_any = false;
    union { unsigned short s[8]; u32x4 u; } pk;
#pragma unroll
    for (int j = 0; j < 8; j++) {
      bool n = (v[j] != v[j]);
      nan_any |= n;
      pk.s[j] = f2bf(n ? 0.f : v[j]);
    }
    *reinterpret_cast<u32x4*>(xc + (size_t)r * 512 + lane * 8) = pk.u;
    unsigned long long bal = __ballot(nan_any);
    if (lane == 0) flags[r] = bal ? 1.f : 0.f;
  }

  // stage w2 (transposed, bf16) into LDS; first K-loop barrier covers readers
  for (int i = threadIdx.x; i < AH * NT; i += 256) {
    int k = i >> 6, n = i & 63;
    w2s[n * 136 + k] = f2bf(w2[i]);
  }
  __syncthreads();  // xc writes drained (vmcnt) + w2s visible

  f32x4 acc[8];
#pragma unroll
  for (int j = 0; j < 8; j++) acc[j] = f32x4{0.f, 0.f, 0.f, 0.f};
  const unsigned short* Ag = xc + (size_t)bm0 * 512;

  for (int ko = 0; ko < 8; ++ko) {
    const unsigned short* Ak = Ag + ko * 64;
    const unsigned short* Bk = w1t + ko * 64;
#pragma unroll
    for (int i = 0; i < 2; i++) {
      int seg = wid * 2 + i;
      int r = seg * 8 + sub;
      int cg = cpos ^ (r & 7);
      gload_lds16(Ak + r * 512 + cg * 8, As + seg * 1024);
    }
#pragma unroll
    for (int i = 0; i < 4; i++) {
      int seg = wid * 4 + i;
      int r = seg * 8 + sub;
      int cg = cpos ^ (r & 7);
      gload_lds16(Bk + r * 512 + cg * 8, Bs + seg * 1024);
    }
    __syncthreads();
#pragma unroll
    for (int ks = 0; ks < 2; ++ks) {
      bf16x8 af = frag_ld(As, wid * 16 + m, ks * 4 + q);
#pragma unroll
      for (int ni = 0; ni < 8; ni++) {
        bf16x8 bfr = frag_ld(Bs, ni * 16 + m, ks * 4 + q);
        acc[ni] = __builtin_amdgcn_mfma_f32_16x16x32_bf16(af, bfr, acc[ni], 0, 0, 0);
      }
    }
    __syncthreads();
  }

  // epilogue 1: bias/ReLU/BN -> hb (bf16, per-wave rows wid*16..wid*16+15)
#pragma unroll
  for (int ni = 0; ni < 8; ni++) {
    int col = ni * 16 + m;
    float bb = b1[col], ga = gam[col], be = bet[col], mm = mu[col];
    float iv = rsqrtf(var[col] + BN_EPS_C);
#pragma unroll
    for (int r4 = 0; r4 < 4; r4++) {
      int rl = wid * 16 + q * 4 + r4;
      float v = acc[ni][r4] + bb;
      v = fmaxf(v, 0.f);
      v = (v - mm) * iv * ga + be;
      hb[rl * 136 + col] = f2bf(v);
    }
  }

  // GEMM2: s[64 rows][64 trees] = hb @ w2s^T ; per-wave m-tile = its own rows
  f32x4 acc2[4];
#pragma unroll
  for (int nt = 0; nt < 4; nt++) acc2[nt] = f32x4{0.f, 0.f, 0.f, 0.f};
#pragma unroll
  for (int ks = 0; ks < 4; ++ks) {
    bf16x8 af = *reinterpret_cast<const bf16x8*>(hb + (wid * 16 + m) * 136 + ks * 32 + q * 8);
#pragma unroll
    for (int nt = 0; nt < 4; nt++) {
      bf16x8 bfr = *reinterpret_cast<const bf16x8*>(w2s + (nt * 16 + m) * 136 + ks * 32 + q * 8);
      acc2[nt] = __builtin_amdgcn_mfma_f32_16x16x32_bf16(af, bfr, acc2[nt], 0, 0, 0);
    }
  }

  // softmax over 64 trees per row (4 n-tiles in-thread x 16 lanes via shfl_xor)
  float b2v[4], cfv[4];
#pragma unroll
  for (int nt = 0; nt < 4; nt++) {
    int col = nt * 16 + m;
    b2v[nt] = b2[col];
    cfv[nt] = SHRINK * rw[col];
  }
#pragma unroll
  for (int reg = 0; reg < 4; ++reg) {
    float s0 = acc2[0][reg] + b2v[0];
    float s1 = acc2[1][reg] + b2v[1];
    float s2 = acc2[2][reg] + b2v[2];
    float s3 = acc2[3][reg] + b2v[3];
    float mx = fmaxf(fmaxf(s0, s1), fmaxf(s2, s3));
#pragma unroll
    for (int o = 1; o < 16; o <<= 1) mx = fmaxf(mx, __shfl_xor(mx, o));
    float e0 = __expf(s0 - mx), e1 = __expf(s1 - mx);
    float e2 = __expf(s2 - mx), e3 = __expf(s3 - mx);
    float sm = e0 + e1 + e2 + e3;
#pragma unroll
    for (int o = 1; o < 16; o <<= 1) sm += __shfl_xor(sm, o);
    float inv = 1.f / sm;
    int row = bm0 + wid * 16 + q * 4 + reg;
    wbt[row * NT + m]      = e0 * inv * cfv[0];
    wbt[row * NT + 16 + m] = e1 * inv * cfv[1];
    wbt[row * NT + 32 + m] = e2 * inv * cfv[2];
    wbt[row * NT + 48 + m] = e3 * inv * cfv[3];
  }
}

// ---------------- main: tree logits + routing + leaf -> per-slice partials ----
// (REVERTED to the round-7/8-verified kernel: 186 us / 96 VGPR. Round 9's
// MFMA leaf-reduce cut VALU 50->35% but added 4 barriers + 2 LDS round-trips
// per tree -> idle 64->105 us, net +20 us. At ~7 waves/CU, in-register fma
// beats LDS round-trip + block barrier.)
// tile: 128 rows x 128 cols (2 trees), BK=64, 4 waves, SINGLE GEMM pass.
// Grid: x = tree-pair (fast), y = row-tile -> co-dispatched blocks share A-tile.
// Epilogue: decisions via LDS (stride 67); miss folded in at WRITE time; leaf
// values via wave-uniform global reads -> SGPRs (R5's LDS-float4 leaf reads
// blew VGPR to 216 -> 1 block/CU). NO atomics (R3). No VGPR cap (R2).
__global__ void __launch_bounds__(256) k_trees(
    const unsigned short* __restrict__ xc,   // [16384][512]
    const unsigned short* __restrict__ twb,  // [64*64][512]
    const float* __restrict__ tree_b,        // [64][63]
    const float* __restrict__ tree_temp,     // [64]
    const float* __restrict__ leaf,          // [64][64][10]
    const float* __restrict__ wbt,           // [16384][64]
    const float* __restrict__ flags,         // [16384]
    unsigned short* __restrict__ part) {     // [16384][32][10] bf16
  __shared__ __align__(16) char smem[34816];
  char* As = smem;                                  // 128x64 bf16 = 16384
  char* Bs = smem + 16384;                          // 128x64 bf16 = 16384
  float* decw = reinterpret_cast<float*>(smem);     // 128 x 67 f32 = 34304 (epilogue)
  int lane = threadIdx.x & 63, wid = threadIdx.x >> 6;
  int bm0 = blockIdx.y * 128;   // row tile
  int t0 = blockIdx.x * 2;      // tree pair (fast grid dim for L2 sharing)
  int m = lane & 15, q = lane >> 4;
  int sub = lane >> 3, cpos = lane & 7;
  int rA0 = wid * 32 + m;
  int row_l = threadIdx.x & 127;
  int h = __builtin_amdgcn_readfirstlane((int)(threadIdx.x >> 7));  // wave-uniform half
  int grow = bm0 + row_l;

  f32x4 acc[2][8];
#pragma unroll
  for (int i = 0; i < 2; i++)
#pragma unroll
    for (int j = 0; j < 8; j++) acc[i][j] = f32x4{0.f, 0.f, 0.f, 0.f};

  const unsigned short* Ag = xc + (size_t)bm0 * 512;
  const unsigned short* Bg = twb + (size_t)t0 * 64 * 512;

  for (int ko = 0; ko < 8; ++ko) {
    const unsigned short* Ak = Ag + ko * 64;
    const unsigned short* Bk = Bg + ko * 64;
#pragma unroll
    for (int i = 0; i < 4; i++) {
      int seg = wid * 4 + i;
      int r = seg * 8 + sub;
      int cg = cpos ^ (r & 7);
      gload_lds16(Ak + r * 512 + cg * 8, As + seg * 1024);
      gload_lds16(Bk + r * 512 + cg * 8, Bs + seg * 1024);
    }
    __syncthreads();
#pragma unroll
    for (int ks = 0; ks < 2; ++ks) {
      bf16x8 af[2];
#pragma unroll
      for (int mi = 0; mi < 2; mi++) af[mi] = frag_ld(As, rA0 + mi * 16, ks * 4 + q);
#pragma unroll
      for (int ni = 0; ni < 8; ni++) {
        bf16x8 bfr = frag_ld(Bs, ni * 16 + m, ks * 4 + q);
#pragma unroll
        for (int mi = 0; mi < 2; mi++)
          acc[mi][ni] = __builtin_amdgcn_mfma_f32_16x16x32_bf16(af[mi], bfr, acc[mi][ni], 0, 0, 0);
      }
    }
    __syncthreads();
  }

  // ---- epilogue ----
  float flv[2][4];
  {
    float4 f0 = *(const float4*)(flags + bm0 + wid * 32 + q * 4);
    float4 f1 = *(const float4*)(flags + bm0 + wid * 32 + 16 + q * 4);
    flv[0][0] = f0.x; flv[0][1] = f0.y; flv[0][2] = f0.z; flv[0][3] = f0.w;
    flv[1][0] = f1.x; flv[1][1] = f1.y; flv[1][2] = f1.z; flv[1][3] = f1.w;
  }
  float2 wpair = *(const float2*)(wbt + grow * 64 + t0);  // prefetch weights
  float pc[10];
#pragma unroll
  for (int c = 0; c < 10; c++) pc[c] = 0.f;

  for (int tt = 0; tt < 2; ++tt) {
    int t = t0 + tt;
    float itemp = 1.f / tree_temp[t];
    float tbv[4];
#pragma unroll
    for (int nl = 0; nl < 4; nl++) {
      int node = nl * 16 + m;
      tbv[nl] = (node < 63) ? tree_b[t * 63 + node] : 0.f;
    }
    __syncthreads();  // previous readers of decw (GEMM tiles / routing) done
#pragma unroll
    for (int mi = 0; mi < 2; mi++) {
#pragma unroll
      for (int nl = 0; nl < 4; nl++) {
        int node = nl * 16 + m;
        f32x4 a = acc[mi][tt * 4 + nl];
#pragma unroll
        for (int r4 = 0; r4 < 4; r4++) {
          int row = wid * 32 + mi * 16 + q * 4 + r4;
          float z = (a[r4] + tbv[nl]) * itemp;
          float sig = __builtin_amdgcn_rcpf(1.f + __expf(-z));
          decw[row * DSTRIDE + node + 1] = (flv[mi][r4] != 0.f) ? 0.5f : sig;
        }
      }
    }
    __syncthreads();

    const float* dr = decw + row_l * DSTRIDE;
    float R[16];
    {
      float d0 = dr[1];
      R[0] = d0;
      R[1] = 1.f - d0;
    }
#pragma unroll
    for (int L = 1; L <= 3; ++L) {
      int half = 1 << L;
#pragma unroll
      for (int g = 0; g < half; g += 2) {
        float2 dd = *reinterpret_cast<const float2*>(dr + half + g);
        float ra = R[g] * dd.x;
        R[g + half] = R[g] - ra;
        R[g] = ra;
        float rb = R[g + 1] * dd.y;
        R[g + 1 + half] = R[g + 1] - rb;
        R[g + 1] = rb;
      }
    }
#pragma unroll
    for (int p = 0; p < 16; p += 2) {
      float2 dd = *reinterpret_cast<const float2*>(dr + 16 + p);
      float da = h ? (1.f - dd.x) : dd.x;
      float db = h ? (1.f - dd.y) : dd.y;
      R[p] *= da;
      R[p + 1] *= db;
    }
    float a10[10];
#pragma unroll
    for (int c = 0; c < 10; c++) a10[c] = 0.f;
    const float* Lf = leaf + (size_t)(t * 64 + 16 * h) * 10;
#pragma unroll
    for (int p = 0; p < 16; p += 2) {
      float2 dd = *reinterpret_cast<const float2*>(dr + 32 + 16 * h + p);
      float rla = R[p] * dd.x, rra = R[p] - rla;
      float rlb = R[p + 1] * dd.y, rrb = R[p + 1] - rlb;
#pragma unroll
      for (int c = 0; c < 10; c++) {
        float s = fmaf(rla, Lf[p * 10 + c], a10[c]);
        s = fmaf(rra, Lf[320 + p * 10 + c], s);
        s = fmaf(rlb, Lf[p * 10 + 10 + c], s);
        a10[c] = fmaf(rrb, Lf[330 + p * 10 + c], s);
      }
    }
    float w = tt ? wpair.y : wpair.x;
#pragma unroll
    for (int c = 0; c < 10; c++) pc[c] = fmaf(w, a10[c], pc[c]);
  }

  __syncthreads();
  float* redbuf = reinterpret_cast<float*>(smem);  // 128 x 10 f32
  if (h == 1) {
#pragma unroll
    for (int c = 0; c < 10; c++) redbuf[row_l * 10 + c] = pc[c];
  }
  __syncthreads();
  if (h == 0) {
    unsigned short* po = part + ((size_t)grow * 32 + blockIdx.x) * 10;
    unsigned wdw[5];
#pragma unroll
    for (int k = 0; k < 5; k++) {
      unsigned lo = f2bf(pc[2 * k] + redbuf[row_l * 10 + 2 * k]);
      unsigned hi = f2bf(pc[2 * k + 1] + redbuf[row_l * 10 + 2 * k + 1]);
      wdw[k] = lo | (hi << 16);
    }
    unsigned* pu = reinterpret_cast<unsigned*>(po);
#pragma unroll
    for (int k = 0; k < 5; k++) pu[k] = wdw[k];
  }
}

// ---------------- final: reduce 32 bf16 slices + softmax ----------------
__global__ void __launch_bounds__(128) k_finish(const unsigned short* __restrict__ part,
                                               float* __restrict__ out) {
  int row = blockIdx.x * 128 + threadIdx.x;
  const uint4* pu = reinterpret_cast<const uint4*>(part + (size_t)row * 320);
  float v[10];
#pragma unroll
  for (int c = 0; c < 10; c++) v[c] = 0.f;
#pragma unroll
  for (int ch = 0; ch < 8; ++ch) {
    uint4 w0 = pu[ch * 5 + 0];
    uint4 w1 = pu[ch * 5 + 1];
    uint4 w2 = pu[ch * 5 + 2];
    uint4 w3 = pu[ch * 5 + 3];
    uint4 w4 = pu[ch * 5 + 4];
    unsigned dw[20] = {w0.x, w0.y, w0.z, w0.w, w1.x, w1.y, w1.z, w1.w,
                       w2.x, w2.y, w2.z, w2.w, w3.x, w3.y, w3.z, w3.w,
                       w4.x, w4.y, w4.z, w4.w};
#pragma unroll
    for (int d = 0; d < 20; d++) {
      int k = d % 5;
      v[2 * k] += bflo(dw[d]);
      v[2 * k + 1] += bfhi(dw[d]);
    }
  }
  float mx = -1e30f;
#pragma unroll
  for (int c = 0; c < 10; c++) mx = fmaxf(mx, v[c]);
  float sm = 0.f;
#pragma unroll
  for (int c = 0; c < 10; c++) {
    v[c] = __expf(v[c] - mx);
    sm += v[c];
  }
  float inv = 1.f / sm;
#pragma unroll
  for (int c = 0; c < 10; c++) out[row * 10 + c] = v[c] * inv;
}

extern "C" void kernel_launch(void* const* d_in, const int* in_sizes, int n_in,
                              void* d_out, int out_size, void* d_ws, size_t ws_size,
                              hipStream_t stream) {
  const float* x    = (const float*)d_in[0];
  const float* w1   = (const float*)d_in[1];
  const float* b1   = (const float*)d_in[2];
  const float* gam  = (const float*)d_in[3];
  const float* bet  = (const float*)d_in[4];
  const float* mu   = (const float*)d_in[5];
  const float* var  = (const float*)d_in[6];
  const float* w2   = (const float*)d_in[7];
  const float* b2   = (const float*)d_in[8];
  const float* tw   = (const float*)d_in[9];
  const float* tb   = (const float*)d_in[10];
  const float* temp = (const float*)d_in[11];
  const float* leaf = (const float*)d_in[12];
  const float* rw   = (const float*)d_in[13];
  float* out = (float*)d_out;

  char* ws = (char*)d_ws;
  unsigned short* xc  = (unsigned short*)(ws);             // 16,777,216 B
  unsigned short* twb = (unsigned short*)(ws + 16777216);  //  4,194,304 B
  unsigned short* w1t = (unsigned short*)(ws + 20971520);  //    131,072 B
  float* wbt  = (float*)(ws + 21102592);                   //  4,194,304 B
  float* flg  = (float*)(ws + 25296896);                   //     65,536 B
  unsigned short* part = (unsigned short*)(ws + 25362432); // 10,485,760 B

  k_prep<<<1280, 256, 0, stream>>>(tw, twb, w1, w1t);
  k_attn<<<256, 256, 0, stream>>>(x, xc, flg, w1t, b1, gam, bet, mu, var,
                                  w2, b2, rw, wbt);
  dim3 g2(32, 128);
  k_trees<<<g2, 256, 0, stream>>>(xc, twb, tb, temp, leaf, wbt, flg, part);
  k_finish<<<128, 128, 0, stream>>>(part, out);
}

// Round 11
// 259.816 us; speedup vs baseline: 1.1960x; 1.1078x over previous
//
#include <hip/hip_runtime.h>
#include <hip/hip_fp16.h>
#include <stdint.h>

#define IN_DIM 512
#define NT 64
#define AH 128
#define NCLS 10
#define BN_EPS_C 1e-5f
#define SHRINK 0.3f
#define HSTRIDE 66   // f16 decision plane stride: 66 h16 = 33 dw, coprime mod 32
#define HPLANE 8448  // 128 * 66 h16 per tree plane

typedef __bf16 bf16x8 __attribute__((ext_vector_type(8)));
typedef float f32x4 __attribute__((ext_vector_type(4)));
typedef unsigned int u32x4 __attribute__((ext_vector_type(4)));

__device__ __forceinline__ unsigned short f2bf(float f) {
  unsigned u = __builtin_bit_cast(unsigned, f);
  u += 0x7fffu + ((u >> 16) & 1u);   // RNE; inputs are NaN-free after NaN-zeroing
  return (unsigned short)(u >> 16);
}

__device__ __forceinline__ float bflo(unsigned w) {
  return __builtin_bit_cast(float, w << 16);
}
__device__ __forceinline__ float bfhi(unsigned w) {
  return __builtin_bit_cast(float, w & 0xffff0000u);
}

__device__ __forceinline__ void gload_lds16(const void* g, void* l) {
  __builtin_amdgcn_global_load_lds(
      (const __attribute__((address_space(1))) void*)g,
      (__attribute__((address_space(3))) void*)l, 16, 0, 0);
}

// read one 16B MFMA fragment from a swizzled [rows][64] bf16 LDS tile
__device__ __forceinline__ bf16x8 frag_ld(const char* lds, int r, int q) {
  return *reinterpret_cast<const bf16x8*>(lds + r * 128 + ((q ^ (r & 7)) * 16));
}

// ---------------- prep: tree_w->bf16(pad), w1->w1t (x handled in k_attn) ----
__global__ void __launch_bounds__(256) k_prep(
    const float* __restrict__ tw, unsigned short* __restrict__ twb,
    const float* __restrict__ w1, unsigned short* __restrict__ w1t) {
  int b = blockIdx.x;
  if (b < 1024) {
    int tid = b * 256 + threadIdx.x;  // 262144
    int o = tid * 8;
    int k = o & 511;
    int nt = o >> 9;
    int node = nt & 63, t = nt >> 6;
    union { unsigned short s[8]; u32x4 u; } pk;
    if (node < 63) {
      const float* p = tw + ((t * 63 + node) * 512 + k);
      float4 a = *(const float4*)p, bb = *(const float4*)(p + 4);
      float v[8] = {a.x, a.y, a.z, a.w, bb.x, bb.y, bb.z, bb.w};
#pragma unroll
      for (int i = 0; i < 8; i++) pk.s[i] = f2bf(v[i]);
    } else {
#pragma unroll
      for (int i = 0; i < 8; i++) pk.s[i] = 0;
    }
    *reinterpret_cast<u32x4*>(twb + o) = pk.u;
  } else {
    int tid = (b - 1024) * 256 + threadIdx.x;  // 65536
    int k = tid & 511, n = tid >> 9;
    w1t[n * 512 + k] = f2bf(w1[k * 128 + n]);
  }
}

// ---------------- fused attention + x conversion (unchanged from R10) -------
__global__ void __launch_bounds__(256) k_attn(
    const float* __restrict__ x, unsigned short* __restrict__ xc,
    float* __restrict__ flags,
    const unsigned short* __restrict__ w1t,
    const float* __restrict__ b1, const float* __restrict__ gam,
    const float* __restrict__ bet, const float* __restrict__ mu,
    const float* __restrict__ var, const float* __restrict__ w2,
    const float* __restrict__ b2, const float* __restrict__ rw,
    float* __restrict__ wbt) {
  __shared__ __align__(16) char smem[59392];
  char* As = smem;                                        // 64x64 bf16 = 8192
  char* Bs = smem + 8192;                                 // 128x64 bf16 = 16384
  unsigned short* hb  = (unsigned short*)(smem + 24576);  // [64][136] bf16 = 17408
  unsigned short* w2s = (unsigned short*)(smem + 41984);  // [64][136] bf16 = 17408
  int lane = threadIdx.x & 63, wid = threadIdx.x >> 6;
  int bm0 = blockIdx.x * 64;
  int m = lane & 15, q = lane >> 4;
  int sub = lane >> 3, cpos = lane & 7;

  // phase 0: x -> xc + flags for this block's 64 rows
  for (int i = 0; i < 16; ++i) {
    int r = bm0 + wid * 16 + i;
    const float* px = x + (size_t)r * 512 + lane * 8;
    float4 a = *(const float4*)px;
    float4 bb = *(const float4*)(px + 4);
    float v[8] = {a.x, a.y, a.z, a.w, bb.x, bb.y, bb.z, bb.w};
    bool nan_any = false;
    union { unsigned short s[8]; u32x4 u; } pk;
#pragma unroll
    for (int j = 0; j < 8; j++) {
      bool n = (v[j] != v[j]);
      nan_any |= n;
      pk.s[j] = f2bf(n ? 0.f : v[j]);
    }
    *reinterpret_cast<u32x4*>(xc + (size_t)r * 512 + lane * 8) = pk.u;
    unsigned long long bal = __ballot(nan_any);
    if (lane == 0) flags[r] = bal ? 1.f : 0.f;
  }

  for (int i = threadIdx.x; i < AH * NT; i += 256) {
    int k = i >> 6, n = i & 63;
    w2s[n * 136 + k] = f2bf(w2[i]);
  }
  __syncthreads();  // xc writes drained (vmcnt) + w2s visible

  f32x4 acc[8];
#pragma unroll
  for (int j = 0; j < 8; j++) acc[j] = f32x4{0.f, 0.f, 0.f, 0.f};
  const unsigned short* Ag = xc + (size_t)bm0 * 512;

  for (int ko = 0; ko < 8; ++ko) {
    const unsigned short* Ak = Ag + ko * 64;
    const unsigned short* Bk = w1t + ko * 64;
#pragma unroll
    for (int i = 0; i < 2; i++) {
      int seg = wid * 2 + i;
      int r = seg * 8 + sub;
      int cg = cpos ^ (r & 7);
      gload_lds16(Ak + r * 512 + cg * 8, As + seg * 1024);
    }
#pragma unroll
    for (int i = 0; i < 4; i++) {
      int seg = wid * 4 + i;
      int r = seg * 8 + sub;
      int cg = cpos ^ (r & 7);
      gload_lds16(Bk + r * 512 + cg * 8, Bs + seg * 1024);
    }
    __syncthreads();
#pragma unroll
    for (int ks = 0; ks < 2; ++ks) {
      bf16x8 af = frag_ld(As, wid * 16 + m, ks * 4 + q);
#pragma unroll
      for (int ni = 0; ni < 8; ni++) {
        bf16x8 bfr = frag_ld(Bs, ni * 16 + m, ks * 4 + q);
        acc[ni] = __builtin_amdgcn_mfma_f32_16x16x32_bf16(af, bfr, acc[ni], 0, 0, 0);
      }
    }
    __syncthreads();
  }

#pragma unroll
  for (int ni = 0; ni < 8; ni++) {
    int col = ni * 16 + m;
    float bb = b1[col], ga = gam[col], be = bet[col], mm = mu[col];
    float iv = rsqrtf(var[col] + BN_EPS_C);
#pragma unroll
    for (int r4 = 0; r4 < 4; r4++) {
      int rl = wid * 16 + q * 4 + r4;
      float v = acc[ni][r4] + bb;
      v = fmaxf(v, 0.f);
      v = (v - mm) * iv * ga + be;
      hb[rl * 136 + col] = f2bf(v);
    }
  }

  f32x4 acc2[4];
#pragma unroll
  for (int nt = 0; nt < 4; nt++) acc2[nt] = f32x4{0.f, 0.f, 0.f, 0.f};
#pragma unroll
  for (int ks = 0; ks < 4; ++ks) {
    bf16x8 af = *reinterpret_cast<const bf16x8*>(hb + (wid * 16 + m) * 136 + ks * 32 + q * 8);
#pragma unroll
    for (int nt = 0; nt < 4; nt++) {
      bf16x8 bfr = *reinterpret_cast<const bf16x8*>(w2s + (nt * 16 + m) * 136 + ks * 32 + q * 8);
      acc2[nt] = __builtin_amdgcn_mfma_f32_16x16x32_bf16(af, bfr, acc2[nt], 0, 0, 0);
    }
  }

  float b2v[4], cfv[4];
#pragma unroll
  for (int nt = 0; nt < 4; nt++) {
    int col = nt * 16 + m;
    b2v[nt] = b2[col];
    cfv[nt] = SHRINK * rw[col];
  }
#pragma unroll
  for (int reg = 0; reg < 4; ++reg) {
    float s0 = acc2[0][reg] + b2v[0];
    float s1 = acc2[1][reg] + b2v[1];
    float s2 = acc2[2][reg] + b2v[2];
    float s3 = acc2[3][reg] + b2v[3];
    float mx = fmaxf(fmaxf(s0, s1), fmaxf(s2, s3));
#pragma unroll
    for (int o = 1; o < 16; o <<= 1) mx = fmaxf(mx, __shfl_xor(mx, o));
    float e0 = __expf(s0 - mx), e1 = __expf(s1 - mx);
    float e2 = __expf(s2 - mx), e3 = __expf(s3 - mx);
    float sm = e0 + e1 + e2 + e3;
#pragma unroll
    for (int o = 1; o < 16; o <<= 1) sm += __shfl_xor(sm, o);
    float inv = 1.f / sm;
    int row = bm0 + wid * 16 + q * 4 + reg;
    wbt[row * NT + m]      = e0 * inv * cfv[0];
    wbt[row * NT + 16 + m] = e1 * inv * cfv[1];
    wbt[row * NT + 32 + m] = e2 * inv * cfv[2];
    wbt[row * NT + 48 + m] = e3 * inv * cfv[3];
  }
}

// ---------------- main: tree logits + routing + leaf -> per-slice partials ----
// GEMM section R7-verified. Epilogue v3: BOTH trees' decisions written as f16
// into two LDS planes ([tree][128][66] h16, stride 66 = 33 dw coprime mod 32,
// even offsets keep half2 reads aligned) -> ONE barrier for both trees (was
// 2x2), routing/leaf for both trees back-to-back (ILP; tree-1 s_loads overlap
// tree-0 compute). Sigmoid = rcp(1+exp2(fma)) with miss folded as u16 cndmask.
// Lessons kept: leaf via wave-uniform s_loads (R5: LDS-float4 -> 216 VGPR);
// no LDS round-trip MFMA epilogue (R9: +4 barriers -> +20 us); no atomics
// (R3); no VGPR cap (R2).
__global__ void __launch_bounds__(256) k_trees(
    const unsigned short* __restrict__ xc,   // [16384][512]
    const unsigned short* __restrict__ twb,  // [64*64][512]
    const float* __restrict__ tree_b,        // [64][63]
    const float* __restrict__ tree_temp,     // [64]
    const float* __restrict__ leaf,          // [64][64][10]
    const float* __restrict__ wbt,           // [16384][64]
    const float* __restrict__ flags,         // [16384]
    unsigned short* __restrict__ part) {     // [16384][32][10] bf16
  __shared__ __align__(16) char smem[33792];
  char* As = smem;                                  // 128x64 bf16 = 16384
  char* Bs = smem + 16384;                          // 128x64 bf16 = 16384
  unsigned short* dh = (unsigned short*)smem;       // 2 planes x 128 x 66 f16 = 33792
  int lane = threadIdx.x & 63, wid = threadIdx.x >> 6;
  int bm0 = blockIdx.y * 128;   // row tile
  int t0 = blockIdx.x * 2;      // tree pair (fast grid dim for L2 sharing)
  int m = lane & 15, q = lane >> 4;
  int sub = lane >> 3, cpos = lane & 7;
  int rA0 = wid * 32 + m;
  int row_l = threadIdx.x & 127;
  int h = __builtin_amdgcn_readfirstlane((int)(threadIdx.x >> 7));  // wave-uniform half
  int grow = bm0 + row_l;

  f32x4 acc[2][8];
#pragma unroll
  for (int i = 0; i < 2; i++)
#pragma unroll
    for (int j = 0; j < 8; j++) acc[i][j] = f32x4{0.f, 0.f, 0.f, 0.f};

  const unsigned short* Ag = xc + (size_t)bm0 * 512;
  const unsigned short* Bg = twb + (size_t)t0 * 64 * 512;

  for (int ko = 0; ko < 8; ++ko) {
    const unsigned short* Ak = Ag + ko * 64;
    const unsigned short* Bk = Bg + ko * 64;
#pragma unroll
    for (int i = 0; i < 4; i++) {
      int seg = wid * 4 + i;
      int r = seg * 8 + sub;
      int cg = cpos ^ (r & 7);
      gload_lds16(Ak + r * 512 + cg * 8, As + seg * 1024);
      gload_lds16(Bk + r * 512 + cg * 8, Bs + seg * 1024);
    }
    __syncthreads();
#pragma unroll
    for (int ks = 0; ks < 2; ++ks) {
      bf16x8 af[2];
#pragma unroll
      for (int mi = 0; mi < 2; mi++) af[mi] = frag_ld(As, rA0 + mi * 16, ks * 4 + q);
#pragma unroll
      for (int ni = 0; ni < 8; ni++) {
        bf16x8 bfr = frag_ld(Bs, ni * 16 + m, ks * 4 + q);
#pragma unroll
        for (int mi = 0; mi < 2; mi++)
          acc[mi][ni] = __builtin_amdgcn_mfma_f32_16x16x32_bf16(af[mi], bfr, acc[mi][ni], 0, 0, 0);
      }
    }
    __syncthreads();
  }
  // (post-loop barrier above: GEMM tile readers done -> dh planes writable)

  // ---- epilogue: write BOTH trees' decisions (f16), one barrier ----
  float flv[2][4];
  {
    float4 f0 = *(const float4*)(flags + bm0 + wid * 32 + q * 4);
    float4 f1 = *(const float4*)(flags + bm0 + wid * 32 + 16 + q * 4);
    flv[0][0] = f0.x; flv[0][1] = f0.y; flv[0][2] = f0.z; flv[0][3] = f0.w;
    flv[1][0] = f1.x; flv[1][1] = f1.y; flv[1][2] = f1.z; flv[1][3] = f1.w;
  }
  float2 wpair = *(const float2*)(wbt + grow * 64 + t0);  // prefetch weights

#pragma unroll
  for (int tt = 0; tt < 2; ++tt) {
    int t = t0 + tt;
    float nk2 = -1.44269504089f / tree_temp[t];  // -itemp*log2(e)
    float ncb[4];
#pragma unroll
    for (int nl = 0; nl < 4; nl++) {
      int node = nl * 16 + m;
      ncb[nl] = ((node < 63) ? tree_b[t * 63 + node] : 0.f) * nk2;
    }
#pragma unroll
    for (int mi = 0; mi < 2; mi++) {
#pragma unroll
      for (int nl = 0; nl < 4; nl++) {
        int node = nl * 16 + m;
        f32x4 a = acc[mi][tt * 4 + nl];
#pragma unroll
        for (int r4 = 0; r4 < 4; r4++) {
          int row = wid * 32 + mi * 16 + q * 4 + r4;
          float e = exp2f(fmaf(a[r4], nk2, ncb[nl]));
          float sig = __builtin_amdgcn_rcpf(1.f + e);
          unsigned short hv = __half_as_ushort(__float2half(sig));
          hv = (flv[mi][r4] != 0.f) ? (unsigned short)0x3800 : hv;  // miss -> 0.5h
          dh[tt * HPLANE + row * HSTRIDE + node + 1] = hv;
        }
      }
    }
  }
  __syncthreads();

  // ---- routing + leaf for both trees (independent chains -> ILP) ----
  float pc[10];
#pragma unroll
  for (int c = 0; c < 10; c++) pc[c] = 0.f;

#pragma unroll
  for (int tt = 0; tt < 2; ++tt) {
    int t = t0 + tt;
    const unsigned short* dr = dh + tt * HPLANE + row_l * HSTRIDE;
    float R[16];
    {
      float d0 = __half2float(__ushort_as_half(dr[1]));
      R[0] = d0;
      R[1] = 1.f - d0;
    }
#pragma unroll
    for (int L = 1; L <= 3; ++L) {
      int half = 1 << L;
#pragma unroll
      for (int g = 0; g < half; g += 2) {
        float2 dd = __half22float2(*reinterpret_cast<const __half2*>(dr + half + g));
        float ra = R[g] * dd.x;
        R[g + half] = R[g] - ra;
        R[g] = ra;
        float rb = R[g + 1] * dd.y;
        R[g + 1 + half] = R[g + 1] - rb;
        R[g + 1] = rb;
      }
    }
#pragma unroll
    for (int p = 0; p < 16; p += 2) {
      float2 dd = __half22float2(*reinterpret_cast<const __half2*>(dr + 16 + p));
      float da = h ? (1.f - dd.x) : dd.x;
      float db = h ? (1.f - dd.y) : dd.y;
      R[p] *= da;
      R[p + 1] *= db;
    }
    float a10[10];
#pragma unroll
    for (int c = 0; c < 10; c++) a10[c] = 0.f;
    const float* Lf = leaf + (size_t)(t * 64 + 16 * h) * 10;
#pragma unroll
    for (int p = 0; p < 16; p += 2) {
      float2 dd = __half22float2(*reinterpret_cast<const __half2*>(dr + 32 + 16 * h + p));
      float rla = R[p] * dd.x, rra = R[p] - rla;
      float rlb = R[p + 1] * dd.y, rrb = R[p + 1] - rlb;
#pragma unroll
      for (int c = 0; c < 10; c++) {
        float s = fmaf(rla, Lf[p * 10 + c], a10[c]);
        s = fmaf(rra, Lf[320 + p * 10 + c], s);
        s = fmaf(rlb, Lf[p * 10 + 10 + c], s);
        a10[c] = fmaf(rrb, Lf[330 + p * 10 + c], s);
      }
    }
    float w = tt ? wpair.y : wpair.x;
#pragma unroll
    for (int c = 0; c < 10; c++) pc[c] = fmaf(w, a10[c], pc[c]);
  }

  // ---- combine halves in LDS, one non-atomic bf16 partial row per block ----
  __syncthreads();
  float* redbuf = reinterpret_cast<float*>(smem);  // 128 x 10 f32
  if (h == 1) {
#pragma unroll
    for (int c = 0; c < 10; c++) redbuf[row_l * 10 + c] = pc[c];
  }
  __syncthreads();
  if (h == 0) {
    unsigned short* po = part + ((size_t)grow * 32 + blockIdx.x) * 10;
    unsigned wdw[5];
#pragma unroll
    for (int k = 0; k < 5; k++) {
      unsigned lo = f2bf(pc[2 * k] + redbuf[row_l * 10 + 2 * k]);
      unsigned hi = f2bf(pc[2 * k + 1] + redbuf[row_l * 10 + 2 * k + 1]);
      wdw[k] = lo | (hi << 16);
    }
    unsigned* pu = reinterpret_cast<unsigned*>(po);
#pragma unroll
    for (int k = 0; k < 5; k++) pu[k] = wdw[k];
  }
}

// ---------------- final: reduce 32 bf16 slices + softmax ----------------
__global__ void __launch_bounds__(128) k_finish(const unsigned short* __restrict__ part,
                                               float* __restrict__ out) {
  int row = blockIdx.x * 128 + threadIdx.x;
  const uint4* pu = reinterpret_cast<const uint4*>(part + (size_t)row * 320);
  float v[10];
#pragma unroll
  for (int c = 0; c < 10; c++) v[c] = 0.f;
#pragma unroll
  for (int ch = 0; ch < 8; ++ch) {
    uint4 w0 = pu[ch * 5 + 0];
    uint4 w1 = pu[ch * 5 + 1];
    uint4 w2 = pu[ch * 5 + 2];
    uint4 w3 = pu[ch * 5 + 3];
    uint4 w4 = pu[ch * 5 + 4];
    unsigned dw[20] = {w0.x, w0.y, w0.z, w0.w, w1.x, w1.y, w1.z, w1.w,
                       w2.x, w2.y, w2.z, w2.w, w3.x, w3.y, w3.z, w3.w,
                       w4.x, w4.y, w4.z, w4.w};
#pragma unroll
    for (int d = 0; d < 20; d++) {
      int k = d % 5;
      v[2 * k] += bflo(dw[d]);
      v[2 * k + 1] += bfhi(dw[d]);
    }
  }
  float mx = -1e30f;
#pragma unroll
  for (int c = 0; c < 10; c++) mx = fmaxf(mx, v[c]);
  float sm = 0.f;
#pragma unroll
  for (int c = 0; c < 10; c++) {
    v[c] = __expf(v[c] - mx);
    sm += v[c];
  }
  float inv = 1.f / sm;
#pragma unroll
  for (int c = 0; c < 10; c++) out[row * 10 + c] = v[c] * inv;
}

extern "C" void kernel_launch(void* const* d_in, const int* in_sizes, int n_in,
                              void* d_out, int out_size, void* d_ws, size_t ws_size,
                              hipStream_t stream) {
  const float* x    = (const float*)d_in[0];
  const float* w1   = (const float*)d_in[1];
  const float* b1   = (const float*)d_in[2];
  const float* gam  = (const float*)d_in[3];
  const float* bet  = (const float*)d_in[4];
  const float* mu   = (const float*)d_in[5];
  const float* var  = (const float*)d_in[6];
  const float* w2   = (const float*)d_in[7];
  const float* b2   = (const float*)d_in[8];
  const float* tw   = (const float*)d_in[9];
  const float* tb   = (const float*)d_in[10];
  const float* temp = (const float*)d_in[11];
  const float* leaf = (const float*)d_in[12];
  const float* rw   = (const float*)d_in[13];
  float* out = (float*)d_out;

  char* ws = (char*)d_ws;
  unsigned short* xc  = (unsigned short*)(ws);             // 16,777,216 B
  unsigned short* twb = (unsigned short*)(ws + 16777216);  //  4,194,304 B
  unsigned short* w1t = (unsigned short*)(ws + 20971520);  //    131,072 B
  float* wbt  = (float*)(ws + 21102592);                   //  4,194,304 B
  float* flg  = (float*)(ws + 25296896);                   //     65,536 B
  unsigned short* part = (unsigned short*)(ws + 25362432); // 10,485,760 B

  k_prep<<<1280, 256, 0, stream>>>(tw, twb, w1, w1t);
  k_attn<<<256, 256, 0, stream>>>(x, xc, flg, w1t, b1, gam, bet, mu, var,
                                  w2, b2, rw, wbt);
  dim3 g2(32, 128);
  k_trees<<<g2, 256, 0, stream>>>(xc, twb, tb, temp, leaf, wbt, flg, part);
  k_finish<<<128, 128, 0, stream>>>(part, out);
}